// Round 1
// baseline (915.214 us; speedup 1.0000x reference)
//
#include <hip/hip_runtime.h>

#define BSZ 256
#define SEQ 2048
#define NT  64

// ---------------------------------------------------------------------------
// Kernel 1: forward algorithm (log-denominator) in exp-domain, one batch per
// 64-thread block (one wave). Lane j owns tag j.
// State: b[j] = exp(alpha[j] - C), C wave-uniform accumulated log-scale.
// Step:  s[j] = sum_i b[i]*E[i][j];  b'[j] = s[j]*exp(emit[j]) (if mask)
// Renormalize every 8 steps: m = max b; b /= m; C += log(m).
// Also fuses the numerator emission gather: lane j accumulates emit[t][j]
// where j == masked tag[t] (for t < SEQ-1; last step handled in kernel 2).
// ---------------------------------------------------------------------------
__global__ __launch_bounds__(64) void crf_forward_kernel(
    const float* __restrict__ logits,
    const int*   __restrict__ tags,
    const int*   __restrict__ mask,
    const float* __restrict__ trans,
    const float* __restrict__ startT,
    const float* __restrict__ endT,
    float* __restrict__ den_out,
    float* __restrict__ numemit_out)
{
    const int b = blockIdx.x;
    const int j = threadIdx.x;            // tag index 0..63
    const float* __restrict__ L  = logits + (size_t)b * SEQ * NT;
    const int*   __restrict__ tg = tags + (size_t)b * SEQ;
    const int*   __restrict__ mk = mask + (size_t)b * SEQ;

    __shared__ float sb[2][NT];

    // E column j: E[i][j] = exp(trans[i][j])
    float Ecol[NT];
#pragma unroll
    for (int i = 0; i < NT; ++i) {
        Ecol[i] = __expf(trans[i * NT + j]);
    }

    // ---- init (t = 0) ----
    float emit0 = L[j];
    int   m0    = mk[0];
    int   tag0  = tg[0] * m0;
    float alpha0 = startT[j] + emit0;

    float mx = alpha0;
#pragma unroll
    for (int d = 1; d < 64; d <<= 1) mx = fmaxf(mx, __shfl_xor(mx, d));
    float C  = mx;
    float bj = __expf(alpha0 - C);

    // numerator emission term for t = 0
    float numacc = (m0 && j == tag0) ? emit0 : 0.0f;

    // ---- main recurrence ----
    for (int t = 1; t < SEQ; ++t) {
        float emit = L[t * NT + j];
        int   mt   = mk[t];
        int   tagt = tg[t] * mt;
        float F    = __expf(emit);

        const int buf = t & 1;
        sb[buf][j] = bj;
        __syncthreads();

        const float4* __restrict__ p = (const float4*)sb[buf];
        float a0 = 0.0f, a1 = 0.0f, a2 = 0.0f, a3 = 0.0f;
#pragma unroll
        for (int i4 = 0; i4 < NT / 4; ++i4) {
            float4 v = p[i4];
            a0 = fmaf(v.x, Ecol[i4 * 4 + 0], a0);
            a1 = fmaf(v.y, Ecol[i4 * 4 + 1], a1);
            a2 = fmaf(v.z, Ecol[i4 * 4 + 2], a2);
            a3 = fmaf(v.w, Ecol[i4 * 4 + 3], a3);
        }
        float s    = (a0 + a1) + (a2 + a3);
        float bnew = s * F;
        bj = mt ? bnew : bj;   // masked step: alpha (and thus b, C) unchanged

        // numerator emission gather (t = 0..SEQ-2 weighted by mask[t])
        if (t < SEQ - 1) {
            numacc += (mt && j == tagt) ? emit : 0.0f;
        }

        // periodic renormalization (pure rescale: C + log(b) invariant)
        if ((t & 7) == 7) {
            float m2 = bj;
#pragma unroll
            for (int d = 1; d < 64; d <<= 1) m2 = fmaxf(m2, __shfl_xor(m2, d));
            bj = bj / m2;
            C += __logf(m2);
        }
    }

    // ---- finalize: den = C + log(sum_j b[j]*exp(end[j])) ----
    float v = bj * __expf(endT[j]);
#pragma unroll
    for (int d = 1; d < 64; d <<= 1) v += __shfl_xor(v, d);
#pragma unroll
    for (int d = 1; d < 64; d <<= 1) numacc += __shfl_xor(numacc, d);

    if (j == 0) {
        den_out[b]     = C + __logf(v);
        numemit_out[b] = numacc;
    }
}

// ---------------------------------------------------------------------------
// Kernel 2: numerator transition/start/end terms + last emission term.
// One batch per 256-thread block; transitions staged in LDS (16 KB).
// ---------------------------------------------------------------------------
__global__ __launch_bounds__(256) void crf_numer_kernel(
    const float* __restrict__ logits,
    const int*   __restrict__ tags,
    const int*   __restrict__ mask,
    const float* __restrict__ trans,
    const float* __restrict__ startT,
    const float* __restrict__ endT,
    float* __restrict__ numtrans_out)
{
    const int b   = blockIdx.x;
    const int tid = threadIdx.x;

    __shared__ float st[NT * NT];
    __shared__ float redf[256];
    __shared__ int   redi[256];

    for (int i = tid; i < NT * NT; i += 256) st[i] = trans[i];
    __syncthreads();

    const int* __restrict__ tg = tags + (size_t)b * SEQ;
    const int* __restrict__ mk = mask + (size_t)b * SEQ;

    float acc = 0.0f;
    int   cnt = 0;
    for (int t = tid; t < SEQ; t += 256) {
        int mt = mk[t];
        cnt += mt;
        if (t < SEQ - 1) {
            int m1 = mk[t + 1];
            int a  = tg[t]     * mt;
            int c  = tg[t + 1] * m1;
            acc += st[a * NT + c] * (float)m1;
        }
    }
    redf[tid] = acc;
    redi[tid] = cnt;
    __syncthreads();
    for (int off = 128; off > 0; off >>= 1) {
        if (tid < off) {
            redf[tid] += redf[tid + off];
            redi[tid] += redi[tid + off];
        }
        __syncthreads();
    }

    if (tid == 0) {
        int   last_idx = redi[0] - 1;
        int   m_last   = mk[SEQ - 1];
        int   tag0     = tg[0] * mk[0];
        int   last_tag = tg[last_idx] * mk[last_idx];
        float r = redf[0] + startT[tag0] + endT[last_tag];
        r += logits[((size_t)b * SEQ + (SEQ - 1)) * NT + last_tag] * (float)m_last;
        numtrans_out[b] = r;
    }
}

// ---------------------------------------------------------------------------
// Kernel 3: final scalar reduction: out = sum_b (numerator - denominator).
// Single block, overwrites d_out (deterministic).
// ---------------------------------------------------------------------------
__global__ __launch_bounds__(256) void crf_reduce_kernel(
    const float* __restrict__ den,
    const float* __restrict__ numemit,
    const float* __restrict__ numtrans,
    float* __restrict__ out)
{
    __shared__ float red[256];
    const int tid = threadIdx.x;
    red[tid] = numemit[tid] + numtrans[tid] - den[tid];
    __syncthreads();
    for (int off = 128; off > 0; off >>= 1) {
        if (tid < off) red[tid] += red[tid + off];
        __syncthreads();
    }
    if (tid == 0) out[0] = red[0];
}

// ---------------------------------------------------------------------------
extern "C" void kernel_launch(void* const* d_in, const int* in_sizes, int n_in,
                              void* d_out, int out_size, void* d_ws, size_t ws_size,
                              hipStream_t stream)
{
    const float* logits = (const float*)d_in[0];
    const int*   tags   = (const int*)  d_in[1];
    const int*   mask   = (const int*)  d_in[2];
    const float* trans  = (const float*)d_in[3];
    const float* startT = (const float*)d_in[4];
    const float* endT   = (const float*)d_in[5];
    float* out = (float*)d_out;

    float* den      = (float*)d_ws;
    float* numemit  = den + BSZ;
    float* numtrans = den + 2 * BSZ;

    crf_forward_kernel<<<BSZ, 64, 0, stream>>>(logits, tags, mask, trans,
                                               startT, endT, den, numemit);
    crf_numer_kernel<<<BSZ, 256, 0, stream>>>(logits, tags, mask, trans,
                                              startT, endT, numtrans);
    crf_reduce_kernel<<<1, 256, 0, stream>>>(den, numemit, numtrans, out);
}